// Round 1
// baseline (498.838 us; speedup 1.0000x reference)
//
#include <hip/hip_runtime.h>

#define ROWS     1024
#define ROW_LEN  65536      // 256*16*16
#define MARGIN   0.01f
#define BLOCK    512

__global__ void zero_out_kernel(float* out) {
    out[0] = 0.0f;
}

__global__ __launch_bounds__(BLOCK)
void contrastive_loss_kernel(const float* __restrict__ z1,
                             const float* __restrict__ z2,
                             float* __restrict__ out) {
    const int row = blockIdx.x;
    const size_t base = (size_t)row * ROW_LEN;
    const float4* __restrict__ a = (const float4*)(z1 + base);
    const float4* __restrict__ b = (const float4*)(z2 + base);

    const int n4 = ROW_LEN / 4;   // 16384 float4 per row
    float acc = 0.0f;

    // 16384 / 512 = 32 iterations per thread; unroll for outstanding loads
    #pragma unroll 4
    for (int i = threadIdx.x; i < n4; i += BLOCK) {
        float4 va = a[i];
        float4 vb = b[i];
        float dx = va.x - vb.x;
        float dy = va.y - vb.y;
        float dz = va.z - vb.z;
        float dw = va.w - vb.w;
        acc += dx * dx + dy * dy + dz * dz + dw * dw;
    }

    // wave-level reduce (64 lanes)
    #pragma unroll
    for (int off = 32; off > 0; off >>= 1)
        acc += __shfl_down(acc, off, 64);

    __shared__ float wave_sums[BLOCK / 64];
    const int lane = threadIdx.x & 63;
    const int wid  = threadIdx.x >> 6;
    if (lane == 0) wave_sums[wid] = acc;
    __syncthreads();

    if (threadIdx.x == 0) {
        float s = 0.0f;
        #pragma unroll
        for (int w = 0; w < BLOCK / 64; ++w) s += wave_sums[w];
        const float hamm   = s * (1.0f / (float)ROW_LEN);
        const float hinged = (hamm > MARGIN) ? (hamm - MARGIN) : 0.0f;
        atomicAdd(out, hinged * (1.0f / (float)ROWS));
    }
}

extern "C" void kernel_launch(void* const* d_in, const int* in_sizes, int n_in,
                              void* d_out, int out_size, void* d_ws, size_t ws_size,
                              hipStream_t stream) {
    const float* z1 = (const float*)d_in[0];
    const float* z2 = (const float*)d_in[1];
    float* out = (float*)d_out;

    // d_out is re-poisoned to 0xAA before every launch — zero it first.
    zero_out_kernel<<<1, 1, 0, stream>>>(out);
    contrastive_loss_kernel<<<ROWS, BLOCK, 0, stream>>>(z1, z2, out);
}